// Round 10
// baseline (134.005 us; speedup 1.0000x reference)
//
#include <hip/hip_runtime.h>
#include <hip/hip_bf16.h>
#include <math.h>

// B=2, N=2048, DIM=1024, H=16, D=64; tokens M=4096; BH=32; K=1024
typedef __attribute__((ext_vector_type(8))) short short8v;     // 8 bf16
typedef __attribute__((ext_vector_type(4))) float f32x4;
typedef unsigned short ushort_t;

__device__ __forceinline__ ushort_t to_bf16(float v) {
    __hip_bfloat16 h = __float2bfloat16(v);
    return *(ushort_t*)&h;
}

__device__ __forceinline__ float bf2f(ushort_t u) {
    unsigned x = ((unsigned)u) << 16;
    return __builtin_bit_cast(float, x);
}

// packed f32x2 -> bf16x2 (RNE), single instruction; low half = a
__device__ __forceinline__ unsigned cvt_pk_bf16(float a, float b) {
    unsigned r;
    asm("v_cvt_pk_bf16_f32 %0, %1, %2" : "=v"(r) : "v"(a), "v"(b));
    return r;
}

__device__ __forceinline__ void load_lds_16B(const void* g, void* l) {
    __builtin_amdgcn_global_load_lds(
        (__attribute__((address_space(1))) unsigned int*)(g),
        (__attribute__((address_space(3))) unsigned int*)(l), 16, 0, 0);
}

// ---------------------------------------------------------------------------
// Fused f32 -> bf16 conversion of x (4.19M), qkv_w (3.15M), proj_w (1.05M).
// ---------------------------------------------------------------------------
__global__ __launch_bounds__(256) void convert_kernel(
    const float* __restrict__ x, const float* __restrict__ wq,
    const float* __restrict__ wp, ushort_t* __restrict__ xb,
    ushort_t* __restrict__ wqb, ushort_t* __restrict__ wpb)
{
    int c = blockIdx.x * 256 + threadIdx.x;
    const float* src; ushort_t* dst; int base;
    if (c < 524288)      { src = x;  dst = xb;  base = c; }
    else if (c < 917504) { src = wq; dst = wqb; base = c - 524288; }
    else                 { src = wp; dst = wpb; base = c - 917504; }
    const float4* s4 = (const float4*)src;
    float4 a = s4[2 * (size_t)base], b = s4[2 * (size_t)base + 1];
    float vals[8] = {a.x, a.y, a.z, a.w, b.x, b.y, b.z, b.w};
    short8v o;
#pragma unroll
    for (int j = 0; j < 8; j++) o[j] = (short)to_bf16(vals[j]);
    *(short8v*)(dst + 8 * (size_t)base) = o;
}

// ---------------------------------------------------------------------------
// bf16 MFMA GEMM, m97 structure, BK=32 (round-6 proven version).
// MODE 0: Q(x0.125*log2e)/K/V^T scatter. MODE 1: f32 C = A @ W^T + bias.
// ---------------------------------------------------------------------------
template <int MODE, int BM, int BN>
__global__ __launch_bounds__(256) void gemm_bf16_kernel(
    const ushort_t* __restrict__ A, const ushort_t* __restrict__ Bw,
    const float* __restrict__ bias, ushort_t* __restrict__ Qb,
    ushort_t* __restrict__ Kb, ushort_t* __restrict__ Vt,
    float* __restrict__ Cout)
{
    constexpr int MT = BM / 32, NT = BN / 32;
    __shared__ __align__(16) ushort_t As[BM * 32];
    __shared__ __align__(16) ushort_t Bs[BN * 32];
    const int t = threadIdx.x;
    const int w = t >> 6, l = t & 63;
    const int lo = l & 15, hi = l >> 4;
    const int wr = w >> 1, wc = w & 1;
    const int m0 = blockIdx.y * BM, n0 = blockIdx.x * BN;
    const int K = 1024;

    const ushort_t* ga = A + (size_t)(m0 + (t >> 2)) * K + (t & 3) * 8;
    const ushort_t* gb = Bw + (size_t)(n0 + (t >> 2)) * K + (t & 3) * 8;

    f32x4 acc[MT][NT] = {};

    for (int k0 = 0; k0 < 1024; k0 += 32) {
#pragma unroll
        for (int i = 0; i < BM / 64; i++)
            load_lds_16B(ga + (size_t)(i * 64) * K + k0, As + (i * 256 + w * 64) * 8);
#pragma unroll
        for (int i = 0; i < BN / 64; i++)
            load_lds_16B(gb + (size_t)(i * 64) * K + k0, Bs + (i * 256 + w * 64) * 8);
        __syncthreads();

        short8v af[MT], bf[NT];
#pragma unroll
        for (int mt = 0; mt < MT; mt++) {
            int r = wr * (BM / 2) + mt * 16 + lo;
            af[mt] = *(const short8v*)&As[r * 32 + hi * 8];
        }
#pragma unroll
        for (int nt = 0; nt < NT; nt++) {
            int r = wc * (BN / 2) + nt * 16 + lo;
            bf[nt] = *(const short8v*)&Bs[r * 32 + hi * 8];
        }
#pragma unroll
        for (int mt = 0; mt < MT; mt++)
#pragma unroll
            for (int nt = 0; nt < NT; nt++)
                acc[mt][nt] = __builtin_amdgcn_mfma_f32_16x16x32_bf16(
                    af[mt], bf[nt], acc[mt][nt], 0, 0, 0);
        __syncthreads();
    }

#pragma unroll
    for (int mt = 0; mt < MT; mt++) {
#pragma unroll
        for (int nt = 0; nt < NT; nt++) {
            int col = n0 + wc * (BN / 2) + nt * 16 + lo;
            float bv = bias[col];
#pragma unroll
            for (int reg = 0; reg < 4; reg++) {
                int row = m0 + wr * (BM / 2) + mt * 16 + hi * 4 + reg;
                float val = acc[mt][nt][reg] + bv;
                if constexpr (MODE == 0) {
                    int bb = row >> 11, n = row & 2047;
                    int which = col >> 10, rem = col & 1023;
                    int h = rem >> 6, d = rem & 63;
                    int bh = bb * 16 + h;
                    if (which == 0)  // 0.125 * log2(e): softmax in exp2 domain
                        Qb[((size_t)bh * 2048 + n) * 64 + d] = to_bf16(val * 0.1803368601f);
                    else if (which == 1)
                        Kb[((size_t)bh * 2048 + n) * 64 + d] = to_bf16(val);
                    else
                        Vt[((size_t)bh * 64 + d) * 2048 + n] = to_bf16(val);
                } else {
                    Cout[(size_t)row * 1024 + col] = val;
                }
            }
        }
    }
}

// ---------------------------------------------------------------------------
// MFMA flash attention v6: split-K x2. grid = 1024 (XCD-swizzled),
// 4 waves x 32 q-rows; each block processes HALF the keys (s*1024..+1024,
// 16 tiles) with the verified v5b loop, then writes NORMALIZED partial
// O_s (bf16, head-major) + per-query (m_s, l_s) f32. combine_kernel merges.
// ---------------------------------------------------------------------------
__global__ __launch_bounds__(256) void attn_mfma_kernel(
    const ushort_t* __restrict__ Qg0, const ushort_t* __restrict__ Kg0,
    const ushort_t* __restrict__ Vg0, ushort_t* __restrict__ op0,
    ushort_t* __restrict__ op1, float* __restrict__ ml)
{
    __shared__ __align__(16) ushort_t Ks[2 * 64 * 64];  // [buf][key][d] swz
    __shared__ __align__(16) ushort_t Vs[2 * 64 * 64];  // [buf][d][permuted k]

    const int t = threadIdx.x;
    const int l = t & 63, w = t >> 6;
    const int lo = l & 15, hi = l >> 4;
    const int lin = (blockIdx.x & 7) * 128 + (blockIdx.x >> 3);
    const int bh = lin >> 5;
    const int unit = lin & 31;
    const int q0 = (unit >> 1) * 128;
    const int s = unit & 1;                    // key half
    const ushort_t* Qg = Qg0 + (size_t)bh * 2048 * 64;
    const ushort_t* Kg = Kg0 + (size_t)bh * 2048 * 64 + (size_t)s * 1024 * 64;
    const ushort_t* Vg = Vg0 + (size_t)bh * 64 * 2048 + (size_t)s * 1024;

    // Q B-fragments: wave covers queries q0 + w*32 + qf*16 + lo
    short8v aq[2][2];
#pragma unroll
    for (int qf = 0; qf < 2; qf++) {
        const ushort_t* qrow = Qg + (size_t)(q0 + w * 32 + qf * 16 + lo) * 64;
        aq[qf][0] = *(const short8v*)(qrow + hi * 8);
        aq[qf][1] = *(const short8v*)(qrow + 32 + hi * 8);
    }

    const int srow = t >> 3, sg = t & 7;
    const int sgs = sg ^ (srow & 7);
    const int gv0 = (sg >> 2) * 4 + (sg & 1) * 2;
    const int vo = ((sg >> 1) & 1) * 4;
    const int vswz0 = srow & 7;
    uint4 rk0, rk1, rv0, rv1;

    f32x4 o_acc[2][4] = {};
    float m_i[2] = {-INFINITY, -INFINITY};
    float l_i[2] = {0.0f, 0.0f};

    {
        rk0 = *(const uint4*)(Kg + (size_t)srow * 64 + sg * 8);
        rk1 = *(const uint4*)(Kg + (size_t)(srow + 32) * 64 + sg * 8);
        rv0 = *(const uint4*)(Vg + (size_t)srow * 2048 + sg * 8);
        rv1 = *(const uint4*)(Vg + (size_t)(srow + 32) * 2048 + sg * 8);
        *(uint4*)&Ks[srow * 64 + sgs * 8] = rk0;
        *(uint4*)&Ks[(srow + 32) * 64 + sgs * 8] = rk1;
        uint2 va0 = {rv0.x, rv0.y}, vb0 = {rv0.z, rv0.w};
        uint2 va1 = {rv1.x, rv1.y}, vb1 = {rv1.z, rv1.w};
        *(uint2*)&Vs[srow * 64 + (gv0 ^ vswz0) * 8 + vo] = va0;
        *(uint2*)&Vs[srow * 64 + ((gv0 + 1) ^ vswz0) * 8 + vo] = vb0;
        *(uint2*)&Vs[(srow + 32) * 64 + (gv0 ^ vswz0) * 8 + vo] = va1;
        *(uint2*)&Vs[(srow + 32) * 64 + ((gv0 + 1) ^ vswz0) * 8 + vo] = vb1;
    }
    __syncthreads();

    for (int kt = 0; kt < 16; kt++) {
        const int bufo = (kt & 1) * 4096;
        if (kt < 15) {
            const int k0n = (kt + 1) * 64;
            rk0 = *(const uint4*)(Kg + (size_t)(k0n + srow) * 64 + sg * 8);
            rk1 = *(const uint4*)(Kg + (size_t)(k0n + srow + 32) * 64 + sg * 8);
            rv0 = *(const uint4*)(Vg + (size_t)srow * 2048 + k0n + sg * 8);
            rv1 = *(const uint4*)(Vg + (size_t)(srow + 32) * 2048 + k0n + sg * 8);
        }

        // S^T = K @ Q^T : lane owns query qf*16+lo; keys nt*16 + hi*4 + reg.
        f32x4 s_acc[2][4];
        __builtin_amdgcn_s_setprio(1);
#pragma unroll
        for (int nt = 0; nt < 4; nt++) {
            f32x4 acc0 = {0.f, 0.f, 0.f, 0.f};
            f32x4 acc1 = {0.f, 0.f, 0.f, 0.f};
#pragma unroll
            for (int kk = 0; kk < 2; kk++) {
                int r = nt * 16 + lo;
                int g = (kk * 4 + hi) ^ (r & 7);
                short8v ak = *(const short8v*)&Ks[bufo + r * 64 + g * 8];
                acc0 = __builtin_amdgcn_mfma_f32_16x16x32_bf16(ak, aq[0][kk], acc0, 0, 0, 0);
                acc1 = __builtin_amdgcn_mfma_f32_16x16x32_bf16(ak, aq[1][kk], acc1, 0, 0, 0);
            }
            s_acc[0][nt] = acc0;
            s_acc[1][nt] = acc1;
        }
        __builtin_amdgcn_s_setprio(0);

        // per-fragment softmax, round-7 verified form
        short8v pa[2][2];
#pragma unroll
        for (int qf = 0; qf < 2; qf++) {
            float pm = fmaxf(
                fmaxf(fmaxf(fmaxf(s_acc[qf][0][0], s_acc[qf][0][1]),
                            fmaxf(s_acc[qf][0][2], s_acc[qf][0][3])),
                      fmaxf(fmaxf(s_acc[qf][1][0], s_acc[qf][1][1]),
                            fmaxf(s_acc[qf][1][2], s_acc[qf][1][3]))),
                fmaxf(fmaxf(fmaxf(s_acc[qf][2][0], s_acc[qf][2][1]),
                            fmaxf(s_acc[qf][2][2], s_acc[qf][2][3])),
                      fmaxf(fmaxf(s_acc[qf][3][0], s_acc[qf][3][1]),
                            fmaxf(s_acc[qf][3][2], s_acc[qf][3][3]))));
            pm = fmaxf(pm, __shfl_xor(pm, 16));
            pm = fmaxf(pm, __shfl_xor(pm, 32));

            if (__any(pm > m_i[qf] + 11.0f)) {
                float mnew = fmaxf(m_i[qf], pm);
                float al = __builtin_amdgcn_exp2f(m_i[qf] - mnew);
                m_i[qf] = mnew;
                l_i[qf] *= al;
                float a0 = __shfl(al, hi * 4 + 0);
                float a1 = __shfl(al, hi * 4 + 1);
                float a2 = __shfl(al, hi * 4 + 2);
                float a3 = __shfl(al, hi * 4 + 3);
#pragma unroll
                for (int dt = 0; dt < 4; dt++) {
                    o_acc[qf][dt][0] *= a0; o_acc[qf][dt][1] *= a1;
                    o_acc[qf][dt][2] *= a2; o_acc[qf][dt][3] *= a3;
                }
            }

            float ps = 0.0f;
#pragma unroll
            for (int nt = 0; nt < 4; nt++)
#pragma unroll
                for (int reg = 0; reg < 4; reg++) {
                    s_acc[qf][nt][reg] =
                        __builtin_amdgcn_exp2f(s_acc[qf][nt][reg] - m_i[qf]);
                    ps += s_acc[qf][nt][reg];
                }
            ps += __shfl_xor(ps, 16);
            ps += __shfl_xor(ps, 32);
            l_i[qf] += ps;

            int4 w0i = {(int)cvt_pk_bf16(s_acc[qf][0][0], s_acc[qf][0][1]),
                        (int)cvt_pk_bf16(s_acc[qf][0][2], s_acc[qf][0][3]),
                        (int)cvt_pk_bf16(s_acc[qf][1][0], s_acc[qf][1][1]),
                        (int)cvt_pk_bf16(s_acc[qf][1][2], s_acc[qf][1][3])};
            int4 w1i = {(int)cvt_pk_bf16(s_acc[qf][2][0], s_acc[qf][2][1]),
                        (int)cvt_pk_bf16(s_acc[qf][2][2], s_acc[qf][2][3]),
                        (int)cvt_pk_bf16(s_acc[qf][3][0], s_acc[qf][3][1]),
                        (int)cvt_pk_bf16(s_acc[qf][3][2], s_acc[qf][3][3])};
            pa[qf][0] = __builtin_bit_cast(short8v, w0i);
            pa[qf][1] = __builtin_bit_cast(short8v, w1i);
        }

        if (kt < 15) {
            const int nxto = 4096 - bufo;
            *(uint4*)&Ks[nxto + srow * 64 + sgs * 8] = rk0;
            *(uint4*)&Ks[nxto + (srow + 32) * 64 + sgs * 8] = rk1;
            uint2 va0 = {rv0.x, rv0.y}, vb0 = {rv0.z, rv0.w};
            uint2 va1 = {rv1.x, rv1.y}, vb1 = {rv1.z, rv1.w};
            *(uint2*)&Vs[nxto + srow * 64 + (gv0 ^ vswz0) * 8 + vo] = va0;
            *(uint2*)&Vs[nxto + srow * 64 + ((gv0 + 1) ^ vswz0) * 8 + vo] = vb0;
            *(uint2*)&Vs[nxto + (srow + 32) * 64 + (gv0 ^ vswz0) * 8 + vo] = va1;
            *(uint2*)&Vs[nxto + (srow + 32) * 64 + ((gv0 + 1) ^ vswz0) * 8 + vo] = vb1;
        }

        // O += P @ V. Each bv read feeds both query fragments.
        __builtin_amdgcn_s_setprio(1);
#pragma unroll
        for (int dt = 0; dt < 4; dt++) {
            int r = dt * 16 + lo;
            short8v bv0 = *(const short8v*)&Vs[bufo + r * 64 + ((0 + hi) ^ (r & 7)) * 8];
            short8v bv1 = *(const short8v*)&Vs[bufo + r * 64 + ((4 + hi) ^ (r & 7)) * 8];
            o_acc[0][dt] = __builtin_amdgcn_mfma_f32_16x16x32_bf16(pa[0][0], bv0, o_acc[0][dt], 0, 0, 0);
            o_acc[0][dt] = __builtin_amdgcn_mfma_f32_16x16x32_bf16(pa[0][1], bv1, o_acc[0][dt], 0, 0, 0);
            o_acc[1][dt] = __builtin_amdgcn_mfma_f32_16x16x32_bf16(pa[1][0], bv0, o_acc[1][dt], 0, 0, 0);
            o_acc[1][dt] = __builtin_amdgcn_mfma_f32_16x16x32_bf16(pa[1][1], bv1, o_acc[1][dt], 0, 0, 0);
        }
        __builtin_amdgcn_s_setprio(0);
        __syncthreads();
    }

    // epilogue: write normalized partial O_s (bf16, head-major) + (m,l)
    ushort_t* opart = s ? op1 : op0;
    const int qbase = q0 + w * 32;
#pragma unroll
    for (int qf = 0; qf < 2; qf++) {
        if (hi == 0) {
            float2 v; v.x = m_i[qf]; v.y = l_i[qf];
            ((float2*)ml)[(size_t)s * 65536 + bh * 2048 + qbase + qf * 16 + lo] = v;
        }
#pragma unroll
        for (int reg = 0; reg < 4; reg++) {
            float lv = __shfl(l_i[qf], hi * 4 + reg);
            float inv = 1.0f / lv;
            int row = qbase + qf * 16 + hi * 4 + reg;
            ushort_t* orow = opart + ((size_t)bh * 2048 + row) * 64;
#pragma unroll
            for (int dt = 0; dt < 4; dt++)
                orow[dt * 16 + lo] = to_bf16(o_acc[qf][dt][reg] * inv);
        }
    }
}

// ---------------------------------------------------------------------------
// Split-K combine: O = b0*O0 + b1*O1, b_s = exp2(m_s-m*)*l_s / sum.
// Writes token-major bf16 aob. 524288 threads (one 16B chunk each).
// ---------------------------------------------------------------------------
__global__ __launch_bounds__(256) void combine_kernel(
    const ushort_t* __restrict__ op0, const ushort_t* __restrict__ op1,
    const float* __restrict__ ml, ushort_t* __restrict__ aob)
{
    int idx = blockIdx.x * 256 + threadIdx.x;
    int bhq = idx >> 3, c = idx & 7;
    const float2* mlp = (const float2*)ml;
    float2 ml0 = mlp[bhq];
    float2 ml1 = mlp[65536 + bhq];
    float mstar = fmaxf(ml0.x, ml1.x);
    float w0 = __builtin_amdgcn_exp2f(ml0.x - mstar) * ml0.y;
    float w1 = __builtin_amdgcn_exp2f(ml1.x - mstar) * ml1.y;
    float inv = 1.0f / (w0 + w1);
    float b0 = w0 * inv, b1 = w1 * inv;
    short8v a = *(const short8v*)(op0 + (size_t)bhq * 64 + c * 8);
    short8v bq = *(const short8v*)(op1 + (size_t)bhq * 64 + c * 8);
    float r[8];
#pragma unroll
    for (int j = 0; j < 8; j++)
        r[j] = b0 * bf2f((ushort_t)a[j]) + b1 * bf2f((ushort_t)bq[j]);
    int4 oi = {(int)cvt_pk_bf16(r[0], r[1]), (int)cvt_pk_bf16(r[2], r[3]),
               (int)cvt_pk_bf16(r[4], r[5]), (int)cvt_pk_bf16(r[6], r[7])};
    int bh = bhq >> 11, n = bhq & 2047;
    int b = bh >> 4, h = bh & 15;
    *(short8v*)(aob + ((size_t)(b * 2048 + n)) * 1024 + h * 64 + c * 8) =
        __builtin_bit_cast(short8v, oi);
}

extern "C" void kernel_launch(void* const* d_in, const int* in_sizes, int n_in,
                              void* d_out, int out_size, void* d_ws, size_t ws_size,
                              hipStream_t stream) {
    const float* x      = (const float*)d_in[0];
    const float* qkv_w  = (const float*)d_in[1];
    const float* qkv_b  = (const float*)d_in[2];
    const float* proj_w = (const float*)d_in[3];
    const float* proj_b = (const float*)d_in[4];
    float* out = (float*)d_out;

    ushort_t* xb  = (ushort_t*)d_ws;        // 4,194,304  x bf16 (dead after qkv
                                            //            GEMM; reused as op0)
    ushort_t* wqb = xb  + 4194304;          // 3,145,728  qkv_w bf16
    ushort_t* wpb = wqb + 3145728;          // 1,048,576  proj_w bf16
    ushort_t* qb  = wpb + 1048576;          // 4,194,304  Q (exp2-scaled)
    ushort_t* kb  = qb  + 4194304;          // 4,194,304  K
    ushort_t* vt  = kb  + 4194304;          // 4,194,304  V^T [BH][64][N]
    ushort_t* aob = vt  + 4194304;          // 4,194,304  attn out [M][1024]
    ushort_t* op0 = xb;                     // partial O half 0 (aliases xb)
    ushort_t* op1 = aob + 4194304;          // 4,194,304  partial O half 1
    float*    ml  = (float*)(op1 + 4194304);// 2 x 65536 x {m,l} f32 (1 MB)

    convert_kernel<<<4096, 256, 0, stream>>>(x, qkv_w, proj_w, xb, wqb, wpb);
    gemm_bf16_kernel<0, 128, 128><<<dim3(24, 32), 256, 0, stream>>>(
        xb, wqb, qkv_b, qb, kb, vt, nullptr);
    attn_mfma_kernel<<<1024, 256, 0, stream>>>(qb, kb, vt, op0, op1, ml);
    combine_kernel<<<2048, 256, 0, stream>>>(op0, op1, ml, aob);
    gemm_bf16_kernel<1, 64, 128><<<dim3(8, 64), 256, 0, stream>>>(
        aob, wpb, proj_b, nullptr, nullptr, nullptr, out);
}

// Round 11
// 126.953 us; speedup vs baseline: 1.0555x; 1.0555x over previous
//
#include <hip/hip_runtime.h>
#include <hip/hip_bf16.h>
#include <math.h>

// B=2, N=2048, DIM=1024, H=16, D=64; tokens M=4096; BH=32; K=1024
typedef __attribute__((ext_vector_type(8))) short short8v;     // 8 bf16
typedef __attribute__((ext_vector_type(4))) float f32x4;
typedef unsigned short ushort_t;

__device__ __forceinline__ ushort_t to_bf16(float v) {
    __hip_bfloat16 h = __float2bfloat16(v);
    return *(ushort_t*)&h;
}

// packed f32x2 -> bf16x2 (RNE), single instruction; low half = a
__device__ __forceinline__ unsigned cvt_pk_bf16(float a, float b) {
    unsigned r;
    asm("v_cvt_pk_bf16_f32 %0, %1, %2" : "=v"(r) : "v"(a), "v"(b));
    return r;
}

__device__ __forceinline__ void load_lds_16B(const void* g, void* l) {
    __builtin_amdgcn_global_load_lds(
        (__attribute__((address_space(1))) unsigned int*)(g),
        (__attribute__((address_space(3))) unsigned int*)(l), 16, 0, 0);
}

// ---------------------------------------------------------------------------
// Fused f32 -> bf16 conversion of x (4.19M), qkv_w (3.15M), proj_w (1.05M).
// ---------------------------------------------------------------------------
__global__ __launch_bounds__(256) void convert_kernel(
    const float* __restrict__ x, const float* __restrict__ wq,
    const float* __restrict__ wp, ushort_t* __restrict__ xb,
    ushort_t* __restrict__ wqb, ushort_t* __restrict__ wpb)
{
    int c = blockIdx.x * 256 + threadIdx.x;
    const float* src; ushort_t* dst; int base;
    if (c < 524288)      { src = x;  dst = xb;  base = c; }
    else if (c < 917504) { src = wq; dst = wqb; base = c - 524288; }
    else                 { src = wp; dst = wpb; base = c - 917504; }
    const float4* s4 = (const float4*)src;
    float4 a = s4[2 * (size_t)base], b = s4[2 * (size_t)base + 1];
    float vals[8] = {a.x, a.y, a.z, a.w, b.x, b.y, b.z, b.w};
    short8v o;
#pragma unroll
    for (int j = 0; j < 8; j++) o[j] = (short)to_bf16(vals[j]);
    *(short8v*)(dst + 8 * (size_t)base) = o;
}

// ---------------------------------------------------------------------------
// bf16 MFMA GEMM, m97 structure, BK=32 (round-6 proven version).
// MODE 0: Q(x0.125*log2e)/K/V^T scatter. MODE 1: f32 C = A @ W^T + bias.
// ---------------------------------------------------------------------------
template <int MODE, int BM, int BN>
__global__ __launch_bounds__(256) void gemm_bf16_kernel(
    const ushort_t* __restrict__ A, const ushort_t* __restrict__ Bw,
    const float* __restrict__ bias, ushort_t* __restrict__ Qb,
    ushort_t* __restrict__ Kb, ushort_t* __restrict__ Vt,
    float* __restrict__ Cout)
{
    constexpr int MT = BM / 32, NT = BN / 32;
    __shared__ __align__(16) ushort_t As[BM * 32];
    __shared__ __align__(16) ushort_t Bs[BN * 32];
    const int t = threadIdx.x;
    const int w = t >> 6, l = t & 63;
    const int lo = l & 15, hi = l >> 4;
    const int wr = w >> 1, wc = w & 1;
    const int m0 = blockIdx.y * BM, n0 = blockIdx.x * BN;
    const int K = 1024;

    const ushort_t* ga = A + (size_t)(m0 + (t >> 2)) * K + (t & 3) * 8;
    const ushort_t* gb = Bw + (size_t)(n0 + (t >> 2)) * K + (t & 3) * 8;

    f32x4 acc[MT][NT] = {};

    for (int k0 = 0; k0 < 1024; k0 += 32) {
#pragma unroll
        for (int i = 0; i < BM / 64; i++)
            load_lds_16B(ga + (size_t)(i * 64) * K + k0, As + (i * 256 + w * 64) * 8);
#pragma unroll
        for (int i = 0; i < BN / 64; i++)
            load_lds_16B(gb + (size_t)(i * 64) * K + k0, Bs + (i * 256 + w * 64) * 8);
        __syncthreads();

        short8v af[MT], bf[NT];
#pragma unroll
        for (int mt = 0; mt < MT; mt++) {
            int r = wr * (BM / 2) + mt * 16 + lo;
            af[mt] = *(const short8v*)&As[r * 32 + hi * 8];
        }
#pragma unroll
        for (int nt = 0; nt < NT; nt++) {
            int r = wc * (BN / 2) + nt * 16 + lo;
            bf[nt] = *(const short8v*)&Bs[r * 32 + hi * 8];
        }
#pragma unroll
        for (int mt = 0; mt < MT; mt++)
#pragma unroll
            for (int nt = 0; nt < NT; nt++)
                acc[mt][nt] = __builtin_amdgcn_mfma_f32_16x16x32_bf16(
                    af[mt], bf[nt], acc[mt][nt], 0, 0, 0);
        __syncthreads();
    }

#pragma unroll
    for (int mt = 0; mt < MT; mt++) {
#pragma unroll
        for (int nt = 0; nt < NT; nt++) {
            int col = n0 + wc * (BN / 2) + nt * 16 + lo;
            float bv = bias[col];
#pragma unroll
            for (int reg = 0; reg < 4; reg++) {
                int row = m0 + wr * (BM / 2) + mt * 16 + hi * 4 + reg;
                float val = acc[mt][nt][reg] + bv;
                if constexpr (MODE == 0) {
                    int bb = row >> 11, n = row & 2047;
                    int which = col >> 10, rem = col & 1023;
                    int h = rem >> 6, d = rem & 63;
                    int bh = bb * 16 + h;
                    if (which == 0)  // 0.125 * log2(e): softmax in exp2 domain
                        Qb[((size_t)bh * 2048 + n) * 64 + d] = to_bf16(val * 0.1803368601f);
                    else if (which == 1)
                        Kb[((size_t)bh * 2048 + n) * 64 + d] = to_bf16(val);
                    else
                        Vt[((size_t)bh * 64 + d) * 2048 + n] = to_bf16(val);
                } else {
                    Cout[(size_t)row * 1024 + col] = val;
                }
            }
        }
    }
}

// ---------------------------------------------------------------------------
// MFMA flash attention v7: 2-deep software pipeline. grid = 512
// (XCD-swizzled), 4 waves x 32 q-rows. Per body T (1 barrier each):
//   write LDS tile T+1 | gload T+2 | barrier | QK(T+1) MFMA | softmax(T)
//   VALU (overlaps QK's matrix-pipe work) | PV(T).
// K double-buffered (slot T&1), V TRIPLE-buffered (slot T%3) so every
// write targets a slot whose last reader finished before the prev barrier.
// Softmax/defer-max/permuted-V math identical to verified round-9 kernel.
// ---------------------------------------------------------------------------
__global__ __launch_bounds__(256) void attn_mfma_kernel(
    const ushort_t* __restrict__ Qg0, const ushort_t* __restrict__ Kg0,
    const ushort_t* __restrict__ Vg0, ushort_t* __restrict__ O)
{
    __shared__ __align__(16) ushort_t Ks[2 * 4096];  // [slot][key][d] swz
    __shared__ __align__(16) ushort_t Vs[3 * 4096];  // [slot][d][permuted k]

    const int t = threadIdx.x;
    const int l = t & 63, w = t >> 6;
    const int lo = l & 15, hi = l >> 4;
    const int lin = (blockIdx.x & 7) * 64 + (blockIdx.x >> 3);
    const int bh = lin >> 4;
    const int q0 = (lin & 15) * 128;
    const ushort_t* Qg = Qg0 + (size_t)bh * 2048 * 64;
    const ushort_t* Kg = Kg0 + (size_t)bh * 2048 * 64;
    const ushort_t* Vg = Vg0 + (size_t)bh * 64 * 2048;

    // Q B-fragments: wave covers queries q0 + w*32 + qf*16 + lo
    short8v aq[2][2];
#pragma unroll
    for (int qf = 0; qf < 2; qf++) {
        const ushort_t* qrow = Qg + (size_t)(q0 + w * 32 + qf * 16 + lo) * 64;
        aq[qf][0] = *(const short8v*)(qrow + hi * 8);
        aq[qf][1] = *(const short8v*)(qrow + 32 + hi * 8);
    }

    const int srow = t >> 3, sg = t & 7;
    const int sgs = sg ^ (srow & 7);
    const int gv0 = (sg >> 2) * 4 + (sg & 1) * 2;
    const int vo = ((sg >> 1) & 1) * 4;
    const int vswz0 = srow & 7;
    uint4 rk0, rk1, rv0, rv1;

    f32x4 o_acc[2][4] = {};
    f32x4 sE[2][4], sO[2][4];
    float m_i[2] = {-INFINITY, -INFINITY};
    float l_i[2] = {0.0f, 0.0f};

    auto gload = [&](int kt) {
        const int k0n = kt * 64;
        rk0 = *(const uint4*)(Kg + (size_t)(k0n + srow) * 64 + sg * 8);
        rk1 = *(const uint4*)(Kg + (size_t)(k0n + srow + 32) * 64 + sg * 8);
        rv0 = *(const uint4*)(Vg + (size_t)srow * 2048 + k0n + sg * 8);
        rv1 = *(const uint4*)(Vg + (size_t)(srow + 32) * 2048 + k0n + sg * 8);
    };
    auto stage_write = [&](int kslot, int vslot) {
        *(uint4*)&Ks[kslot * 4096 + srow * 64 + sgs * 8] = rk0;
        *(uint4*)&Ks[kslot * 4096 + (srow + 32) * 64 + sgs * 8] = rk1;
        uint2 va0 = {rv0.x, rv0.y}, vb0 = {rv0.z, rv0.w};
        uint2 va1 = {rv1.x, rv1.y}, vb1 = {rv1.z, rv1.w};
        *(uint2*)&Vs[vslot * 4096 + srow * 64 + (gv0 ^ vswz0) * 8 + vo] = va0;
        *(uint2*)&Vs[vslot * 4096 + srow * 64 + ((gv0 + 1) ^ vswz0) * 8 + vo] = vb0;
        *(uint2*)&Vs[vslot * 4096 + (srow + 32) * 64 + (gv0 ^ vswz0) * 8 + vo] = va1;
        *(uint2*)&Vs[vslot * 4096 + (srow + 32) * 64 + ((gv0 + 1) ^ vswz0) * 8 + vo] = vb1;
    };
    auto qk = [&](f32x4 (&sd)[2][4], int kslot) {
        __builtin_amdgcn_s_setprio(1);
#pragma unroll
        for (int nt = 0; nt < 4; nt++) {
            f32x4 a0 = {0.f, 0.f, 0.f, 0.f};
            f32x4 a1 = {0.f, 0.f, 0.f, 0.f};
#pragma unroll
            for (int kk = 0; kk < 2; kk++) {
                int r = nt * 16 + lo;
                int g = (kk * 4 + hi) ^ (r & 7);
                short8v ak = *(const short8v*)&Ks[kslot * 4096 + r * 64 + g * 8];
                a0 = __builtin_amdgcn_mfma_f32_16x16x32_bf16(ak, aq[0][kk], a0, 0, 0, 0);
                a1 = __builtin_amdgcn_mfma_f32_16x16x32_bf16(ak, aq[1][kk], a1, 0, 0, 0);
            }
            sd[0][nt] = a0;
            sd[1][nt] = a1;
        }
        __builtin_amdgcn_s_setprio(0);
    };
    // softmax on sc (in place) -> pa, then PV from Vs[vslot]
    auto softmax_pv = [&](f32x4 (&sc)[2][4], int vslot) {
        short8v pa[2][2];
#pragma unroll
        for (int qf = 0; qf < 2; qf++) {
            float pm = fmaxf(
                fmaxf(fmaxf(fmaxf(sc[qf][0][0], sc[qf][0][1]),
                            fmaxf(sc[qf][0][2], sc[qf][0][3])),
                      fmaxf(fmaxf(sc[qf][1][0], sc[qf][1][1]),
                            fmaxf(sc[qf][1][2], sc[qf][1][3]))),
                fmaxf(fmaxf(fmaxf(sc[qf][2][0], sc[qf][2][1]),
                            fmaxf(sc[qf][2][2], sc[qf][2][3])),
                      fmaxf(fmaxf(sc[qf][3][0], sc[qf][3][1]),
                            fmaxf(sc[qf][3][2], sc[qf][3][3]))));
            pm = fmaxf(pm, __shfl_xor(pm, 16));
            pm = fmaxf(pm, __shfl_xor(pm, 32));

            if (__any(pm > m_i[qf] + 11.0f)) {
                float mnew = fmaxf(m_i[qf], pm);
                float al = __builtin_amdgcn_exp2f(m_i[qf] - mnew);
                m_i[qf] = mnew;
                l_i[qf] *= al;
                float a0 = __shfl(al, hi * 4 + 0);
                float a1 = __shfl(al, hi * 4 + 1);
                float a2 = __shfl(al, hi * 4 + 2);
                float a3 = __shfl(al, hi * 4 + 3);
#pragma unroll
                for (int dt = 0; dt < 4; dt++) {
                    o_acc[qf][dt][0] *= a0; o_acc[qf][dt][1] *= a1;
                    o_acc[qf][dt][2] *= a2; o_acc[qf][dt][3] *= a3;
                }
            }

            float ps = 0.0f;
#pragma unroll
            for (int nt = 0; nt < 4; nt++)
#pragma unroll
                for (int reg = 0; reg < 4; reg++) {
                    sc[qf][nt][reg] =
                        __builtin_amdgcn_exp2f(sc[qf][nt][reg] - m_i[qf]);
                    ps += sc[qf][nt][reg];
                }
            ps += __shfl_xor(ps, 16);
            ps += __shfl_xor(ps, 32);
            l_i[qf] += ps;

            int4 w0i = {(int)cvt_pk_bf16(sc[qf][0][0], sc[qf][0][1]),
                        (int)cvt_pk_bf16(sc[qf][0][2], sc[qf][0][3]),
                        (int)cvt_pk_bf16(sc[qf][1][0], sc[qf][1][1]),
                        (int)cvt_pk_bf16(sc[qf][1][2], sc[qf][1][3])};
            int4 w1i = {(int)cvt_pk_bf16(sc[qf][2][0], sc[qf][2][1]),
                        (int)cvt_pk_bf16(sc[qf][2][2], sc[qf][2][3]),
                        (int)cvt_pk_bf16(sc[qf][3][0], sc[qf][3][1]),
                        (int)cvt_pk_bf16(sc[qf][3][2], sc[qf][3][3])};
            pa[qf][0] = __builtin_bit_cast(short8v, w0i);
            pa[qf][1] = __builtin_bit_cast(short8v, w1i);
        }

        __builtin_amdgcn_s_setprio(1);
#pragma unroll
        for (int dt = 0; dt < 4; dt++) {
            int r = dt * 16 + lo;
            short8v bv0 = *(const short8v*)&Vs[vslot * 4096 + r * 64 + ((0 + hi) ^ (r & 7)) * 8];
            short8v bv1 = *(const short8v*)&Vs[vslot * 4096 + r * 64 + ((4 + hi) ^ (r & 7)) * 8];
            o_acc[0][dt] = __builtin_amdgcn_mfma_f32_16x16x32_bf16(pa[0][0], bv0, o_acc[0][dt], 0, 0, 0);
            o_acc[0][dt] = __builtin_amdgcn_mfma_f32_16x16x32_bf16(pa[0][1], bv1, o_acc[0][dt], 0, 0, 0);
            o_acc[1][dt] = __builtin_amdgcn_mfma_f32_16x16x32_bf16(pa[1][0], bv0, o_acc[1][dt], 0, 0, 0);
            o_acc[1][dt] = __builtin_amdgcn_mfma_f32_16x16x32_bf16(pa[1][1], bv1, o_acc[1][dt], 0, 0, 0);
        }
        __builtin_amdgcn_s_setprio(0);
    };

    // prologue: tile 0 -> slots (K0, V0); tile 1 in regs; QK(0) -> sE
    gload(0);
    stage_write(0, 0);
    gload(1);
    __syncthreads();
    qk(sE, 0);

    int v0 = 0;
    for (int ti = 0; ti < 16; ti++) {
        const int T = 2 * ti;
        int v1 = v0 + 1; if (v1 == 3) v1 = 0;
        int v2 = v1 + 1; if (v2 == 3) v2 = 0;

        // even body: cur = sE (tile T), next = sO (tile T+1, K slot 1)
        stage_write(1, v1);                 // tile T+1 (T+1 <= 31 always here)
        if (T + 2 < 32) gload(T + 2);
        __syncthreads();
        qk(sO, 1);
        softmax_pv(sE, v0);

        // odd body: cur = sO (tile T+1), next = sE (tile T+2, K slot 0)
        if (T + 2 < 32) stage_write(0, v2); // tile T+2
        if (T + 3 < 32) gload(T + 3);
        __syncthreads();
        if (T + 2 < 32) qk(sE, 0);
        softmax_pv(sO, v1);

        v0 = v2;
    }

    // epilogue: normalize (broadcast l from the lane owning each query row)
    const int b = bh >> 4, h = bh & 15;
#pragma unroll
    for (int qf = 0; qf < 2; qf++) {
#pragma unroll
        for (int reg = 0; reg < 4; reg++) {
            float lv = __shfl(l_i[qf], hi * 4 + reg);
            float inv = 1.0f / lv;
            int row = q0 + w * 32 + qf * 16 + hi * 4 + reg;
            ushort_t* orow = O + ((size_t)(b * 2048 + row)) * 1024 + h * 64;
#pragma unroll
            for (int dt = 0; dt < 4; dt++)
                orow[dt * 16 + lo] = to_bf16(o_acc[qf][dt][reg] * inv);
        }
    }
}

extern "C" void kernel_launch(void* const* d_in, const int* in_sizes, int n_in,
                              void* d_out, int out_size, void* d_ws, size_t ws_size,
                              hipStream_t stream) {
    const float* x      = (const float*)d_in[0];
    const float* qkv_w  = (const float*)d_in[1];
    const float* qkv_b  = (const float*)d_in[2];
    const float* proj_w = (const float*)d_in[3];
    const float* proj_b = (const float*)d_in[4];
    float* out = (float*)d_out;

    ushort_t* xb  = (ushort_t*)d_ws;        // 4,194,304  x bf16
    ushort_t* wqb = xb  + 4194304;          // 3,145,728  qkv_w bf16
    ushort_t* wpb = wqb + 3145728;          // 1,048,576  proj_w bf16
    ushort_t* qb  = wpb + 1048576;          // 4,194,304  Q (exp2-scaled)
    ushort_t* kb  = qb  + 4194304;          // 4,194,304  K
    ushort_t* vt  = kb  + 4194304;          // 4,194,304  V^T [BH][64][N]
    ushort_t* aob = vt  + 4194304;          // 4,194,304  attn out [M][1024]

    convert_kernel<<<4096, 256, 0, stream>>>(x, qkv_w, proj_w, xb, wqb, wpb);
    gemm_bf16_kernel<0, 128, 128><<<dim3(24, 32), 256, 0, stream>>>(
        xb, wqb, qkv_b, qb, kb, vt, nullptr);
    attn_mfma_kernel<<<512, 256, 0, stream>>>(qb, kb, vt, aob);
    gemm_bf16_kernel<1, 64, 128><<<dim3(8, 64), 256, 0, stream>>>(
        aob, wpb, proj_b, nullptr, nullptr, nullptr, out);
}

// Round 12
// 122.771 us; speedup vs baseline: 1.0915x; 1.0341x over previous
//
#include <hip/hip_runtime.h>
#include <hip/hip_bf16.h>
#include <math.h>

// B=2, N=2048, DIM=1024, H=16, D=64; tokens M=4096; BH=32; K=1024
typedef __attribute__((ext_vector_type(8))) short short8v;     // 8 bf16
typedef __attribute__((ext_vector_type(4))) float f32x4;
typedef unsigned short ushort_t;

__device__ __forceinline__ ushort_t to_bf16(float v) {
    __hip_bfloat16 h = __float2bfloat16(v);
    return *(ushort_t*)&h;
}

// packed f32x2 -> bf16x2 (RNE), single instruction; low half = a
__device__ __forceinline__ unsigned cvt_pk_bf16(float a, float b) {
    unsigned r;
    asm("v_cvt_pk_bf16_f32 %0, %1, %2" : "=v"(r) : "v"(a), "v"(b));
    return r;
}

__device__ __forceinline__ void load_lds_16B(const void* g, void* l) {
    __builtin_amdgcn_global_load_lds(
        (__attribute__((address_space(1))) unsigned int*)(g),
        (__attribute__((address_space(3))) unsigned int*)(l), 16, 0, 0);
}

// ---------------------------------------------------------------------------
// Fused f32 -> bf16 conversion of x (4.19M), qkv_w (3.15M), proj_w (1.05M).
// ---------------------------------------------------------------------------
__global__ __launch_bounds__(256) void convert_kernel(
    const float* __restrict__ x, const float* __restrict__ wq,
    const float* __restrict__ wp, ushort_t* __restrict__ xb,
    ushort_t* __restrict__ wqb, ushort_t* __restrict__ wpb)
{
    int c = blockIdx.x * 256 + threadIdx.x;
    const float* src; ushort_t* dst; int base;
    if (c < 524288)      { src = x;  dst = xb;  base = c; }
    else if (c < 917504) { src = wq; dst = wqb; base = c - 524288; }
    else                 { src = wp; dst = wpb; base = c - 917504; }
    const float4* s4 = (const float4*)src;
    float4 a = s4[2 * (size_t)base], b = s4[2 * (size_t)base + 1];
    float vals[8] = {a.x, a.y, a.z, a.w, b.x, b.y, b.z, b.w};
    short8v o;
#pragma unroll
    for (int j = 0; j < 8; j++) o[j] = (short)to_bf16(vals[j]);
    *(short8v*)(dst + 8 * (size_t)base) = o;
}

// ---------------------------------------------------------------------------
// bf16 MFMA GEMM, m97 structure, BK=32.
// MODE 0: 1D grid 768, XCD-chunked (96 consecutive tiles per XCD for A/B
//         panel L2 locality); Q(x0.125*log2e)/K/V^T scatter.
// MODE 1: 2D grid; f32 C = A @ W^T + bias.
// ---------------------------------------------------------------------------
template <int MODE, int BM, int BN>
__global__ __launch_bounds__(256) void gemm_bf16_kernel(
    const ushort_t* __restrict__ A, const ushort_t* __restrict__ Bw,
    const float* __restrict__ bias, ushort_t* __restrict__ Qb,
    ushort_t* __restrict__ Kb, ushort_t* __restrict__ Vt,
    float* __restrict__ Cout)
{
    constexpr int MT = BM / 32, NT = BN / 32;
    __shared__ __align__(16) ushort_t As[BM * 32];
    __shared__ __align__(16) ushort_t Bs[BN * 32];
    const int t = threadIdx.x;
    const int w = t >> 6, l = t & 63;
    const int lo = l & 15, hi = l >> 4;
    const int wr = w >> 1, wc = w & 1;
    int m0, n0;
    if constexpr (MODE == 0) {
        // bijective XCD chunking: 768 blocks = 8 XCDs x 96
        int lin = (blockIdx.x & 7) * 96 + (blockIdx.x >> 3);
        m0 = (lin / 24) * BM;
        n0 = (lin % 24) * BN;
    } else {
        m0 = blockIdx.y * BM;
        n0 = blockIdx.x * BN;
    }
    const int K = 1024;

    const ushort_t* ga = A + (size_t)(m0 + (t >> 2)) * K + (t & 3) * 8;
    const ushort_t* gb = Bw + (size_t)(n0 + (t >> 2)) * K + (t & 3) * 8;

    f32x4 acc[MT][NT] = {};

    for (int k0 = 0; k0 < 1024; k0 += 32) {
#pragma unroll
        for (int i = 0; i < BM / 64; i++)
            load_lds_16B(ga + (size_t)(i * 64) * K + k0, As + (i * 256 + w * 64) * 8);
#pragma unroll
        for (int i = 0; i < BN / 64; i++)
            load_lds_16B(gb + (size_t)(i * 64) * K + k0, Bs + (i * 256 + w * 64) * 8);
        __syncthreads();

        short8v af[MT], bf[NT];
#pragma unroll
        for (int mt = 0; mt < MT; mt++) {
            int r = wr * (BM / 2) + mt * 16 + lo;
            af[mt] = *(const short8v*)&As[r * 32 + hi * 8];
        }
#pragma unroll
        for (int nt = 0; nt < NT; nt++) {
            int r = wc * (BN / 2) + nt * 16 + lo;
            bf[nt] = *(const short8v*)&Bs[r * 32 + hi * 8];
        }
#pragma unroll
        for (int mt = 0; mt < MT; mt++)
#pragma unroll
            for (int nt = 0; nt < NT; nt++)
                acc[mt][nt] = __builtin_amdgcn_mfma_f32_16x16x32_bf16(
                    af[mt], bf[nt], acc[mt][nt], 0, 0, 0);
        __syncthreads();
    }

#pragma unroll
    for (int mt = 0; mt < MT; mt++) {
#pragma unroll
        for (int nt = 0; nt < NT; nt++) {
            int col = n0 + wc * (BN / 2) + nt * 16 + lo;
            float bv = bias[col];
#pragma unroll
            for (int reg = 0; reg < 4; reg++) {
                int row = m0 + wr * (BM / 2) + mt * 16 + hi * 4 + reg;
                float val = acc[mt][nt][reg] + bv;
                if constexpr (MODE == 0) {
                    int bb = row >> 11, n = row & 2047;
                    int which = col >> 10, rem = col & 1023;
                    int h = rem >> 6, d = rem & 63;
                    int bh = bb * 16 + h;
                    if (which == 0)  // 0.125 * log2(e): softmax in exp2 domain
                        Qb[((size_t)bh * 2048 + n) * 64 + d] = to_bf16(val * 0.1803368601f);
                    else if (which == 1)
                        Kb[((size_t)bh * 2048 + n) * 64 + d] = to_bf16(val);
                    else
                        Vt[((size_t)bh * 64 + d) * 2048 + n] = to_bf16(val);
                } else {
                    Cout[(size_t)row * 1024 + col] = val;
                }
            }
        }
    }
}

// ---------------------------------------------------------------------------
// MFMA flash attention v8. grid = 512 (XCD-swizzled), 4 waves x 32 q-rows
// (2 Q fragments/wave). Changes vs v5b (verified round 9):
//  - deferred l: per-lane partial sums (no per-tile shfl reduce); cross-lane
//    reduce once in epilogue. Valid because m is row-uniform every tile.
//  - rescale branch gated on lane-LOCAL max (__any is the same predicate as
//    the row-reduced version); cross-lane max reduce only inside the branch.
// Common-path tiles have zero cross-lane ops. P in registers with
// permuted-column V, K/V dbuf + async-stage, 1 barrier/tile.
// ---------------------------------------------------------------------------
__global__ __launch_bounds__(256) void attn_mfma_kernel(
    const ushort_t* __restrict__ Qg0, const ushort_t* __restrict__ Kg0,
    const ushort_t* __restrict__ Vg0, ushort_t* __restrict__ O)
{
    __shared__ __align__(16) ushort_t Ks[2 * 64 * 64];  // [buf][key][d] swz
    __shared__ __align__(16) ushort_t Vs[2 * 64 * 64];  // [buf][d][permuted k]

    const int t = threadIdx.x;
    const int l = t & 63, w = t >> 6;
    const int lo = l & 15, hi = l >> 4;
    const int lin = (blockIdx.x & 7) * 64 + (blockIdx.x >> 3);
    const int bh = lin >> 4;
    const int q0 = (lin & 15) * 128;
    const ushort_t* Qg = Qg0 + (size_t)bh * 2048 * 64;
    const ushort_t* Kg = Kg0 + (size_t)bh * 2048 * 64;
    const ushort_t* Vg = Vg0 + (size_t)bh * 64 * 2048;

    // Q B-fragments: wave covers queries q0 + w*32 + qf*16 + lo
    short8v aq[2][2];
#pragma unroll
    for (int qf = 0; qf < 2; qf++) {
        const ushort_t* qrow = Qg + (size_t)(q0 + w * 32 + qf * 16 + lo) * 64;
        aq[qf][0] = *(const short8v*)(qrow + hi * 8);
        aq[qf][1] = *(const short8v*)(qrow + 32 + hi * 8);
    }

    const int srow = t >> 3, sg = t & 7;
    const int sgs = sg ^ (srow & 7);
    const int gv0 = (sg >> 2) * 4 + (sg & 1) * 2;
    const int vo = ((sg >> 1) & 1) * 4;
    const int vswz0 = srow & 7;
    uint4 rk0, rk1, rv0, rv1;

    f32x4 o_acc[2][4] = {};
    float m_i[2] = {-INFINITY, -INFINITY};
    float lp[2] = {0.0f, 0.0f};   // per-lane PARTIAL l (own 16 keys)

    {
        rk0 = *(const uint4*)(Kg + (size_t)srow * 64 + sg * 8);
        rk1 = *(const uint4*)(Kg + (size_t)(srow + 32) * 64 + sg * 8);
        rv0 = *(const uint4*)(Vg + (size_t)srow * 2048 + sg * 8);
        rv1 = *(const uint4*)(Vg + (size_t)(srow + 32) * 2048 + sg * 8);
        *(uint4*)&Ks[srow * 64 + sgs * 8] = rk0;
        *(uint4*)&Ks[(srow + 32) * 64 + sgs * 8] = rk1;
        uint2 va0 = {rv0.x, rv0.y}, vb0 = {rv0.z, rv0.w};
        uint2 va1 = {rv1.x, rv1.y}, vb1 = {rv1.z, rv1.w};
        *(uint2*)&Vs[srow * 64 + (gv0 ^ vswz0) * 8 + vo] = va0;
        *(uint2*)&Vs[srow * 64 + ((gv0 + 1) ^ vswz0) * 8 + vo] = vb0;
        *(uint2*)&Vs[(srow + 32) * 64 + (gv0 ^ vswz0) * 8 + vo] = va1;
        *(uint2*)&Vs[(srow + 32) * 64 + ((gv0 + 1) ^ vswz0) * 8 + vo] = vb1;
    }
    __syncthreads();

    for (int kt = 0; kt < 32; kt++) {
        const int bufo = (kt & 1) * 4096;
        if (kt < 31) {
            const int k0n = (kt + 1) * 64;
            rk0 = *(const uint4*)(Kg + (size_t)(k0n + srow) * 64 + sg * 8);
            rk1 = *(const uint4*)(Kg + (size_t)(k0n + srow + 32) * 64 + sg * 8);
            rv0 = *(const uint4*)(Vg + (size_t)srow * 2048 + k0n + sg * 8);
            rv1 = *(const uint4*)(Vg + (size_t)(srow + 32) * 2048 + k0n + sg * 8);
        }

        // S^T = K @ Q^T : lane owns query qf*16+lo; keys nt*16 + hi*4 + reg.
        f32x4 s_acc[2][4];
        __builtin_amdgcn_s_setprio(1);
#pragma unroll
        for (int nt = 0; nt < 4; nt++) {
            f32x4 acc0 = {0.f, 0.f, 0.f, 0.f};
            f32x4 acc1 = {0.f, 0.f, 0.f, 0.f};
#pragma unroll
            for (int kk = 0; kk < 2; kk++) {
                int r = nt * 16 + lo;
                int g = (kk * 4 + hi) ^ (r & 7);
                short8v ak = *(const short8v*)&Ks[bufo + r * 64 + g * 8];
                acc0 = __builtin_amdgcn_mfma_f32_16x16x32_bf16(ak, aq[0][kk], acc0, 0, 0, 0);
                acc1 = __builtin_amdgcn_mfma_f32_16x16x32_bf16(ak, aq[1][kk], acc1, 0, 0, 0);
            }
            s_acc[0][nt] = acc0;
            s_acc[1][nt] = acc1;
        }
        __builtin_amdgcn_s_setprio(0);

        // per-fragment softmax: lane-local except the rare rescale branch
        short8v pa[2][2];
#pragma unroll
        for (int qf = 0; qf < 2; qf++) {
            float lmax = fmaxf(
                fmaxf(fmaxf(fmaxf(s_acc[qf][0][0], s_acc[qf][0][1]),
                            fmaxf(s_acc[qf][0][2], s_acc[qf][0][3])),
                      fmaxf(fmaxf(s_acc[qf][1][0], s_acc[qf][1][1]),
                            fmaxf(s_acc[qf][1][2], s_acc[qf][1][3]))),
                fmaxf(fmaxf(fmaxf(s_acc[qf][2][0], s_acc[qf][2][1]),
                            fmaxf(s_acc[qf][2][2], s_acc[qf][2][3])),
                      fmaxf(fmaxf(s_acc[qf][3][0], s_acc[qf][3][1]),
                            fmaxf(s_acc[qf][3][2], s_acc[qf][3][3]))));

            if (__any(lmax > m_i[qf] + 11.0f)) {   // same predicate as row-max
                float pm = fmaxf(lmax, __shfl_xor(lmax, 16));
                pm = fmaxf(pm, __shfl_xor(pm, 32));
                float mnew = fmaxf(m_i[qf], pm);
                float al = __builtin_amdgcn_exp2f(m_i[qf] - mnew);
                m_i[qf] = mnew;
                lp[qf] *= al;
                float a0 = __shfl(al, hi * 4 + 0);
                float a1 = __shfl(al, hi * 4 + 1);
                float a2 = __shfl(al, hi * 4 + 2);
                float a3 = __shfl(al, hi * 4 + 3);
#pragma unroll
                for (int dt = 0; dt < 4; dt++) {
                    o_acc[qf][dt][0] *= a0; o_acc[qf][dt][1] *= a1;
                    o_acc[qf][dt][2] *= a2; o_acc[qf][dt][3] *= a3;
                }
            }

            float ps = 0.0f;
#pragma unroll
            for (int nt = 0; nt < 4; nt++)
#pragma unroll
                for (int reg = 0; reg < 4; reg++) {
                    s_acc[qf][nt][reg] =
                        __builtin_amdgcn_exp2f(s_acc[qf][nt][reg] - m_i[qf]);
                    ps += s_acc[qf][nt][reg];
                }
            lp[qf] += ps;   // per-lane partial; cross-lane reduce in epilogue

            int4 w0i = {(int)cvt_pk_bf16(s_acc[qf][0][0], s_acc[qf][0][1]),
                        (int)cvt_pk_bf16(s_acc[qf][0][2], s_acc[qf][0][3]),
                        (int)cvt_pk_bf16(s_acc[qf][1][0], s_acc[qf][1][1]),
                        (int)cvt_pk_bf16(s_acc[qf][1][2], s_acc[qf][1][3])};
            int4 w1i = {(int)cvt_pk_bf16(s_acc[qf][2][0], s_acc[qf][2][1]),
                        (int)cvt_pk_bf16(s_acc[qf][2][2], s_acc[qf][2][3]),
                        (int)cvt_pk_bf16(s_acc[qf][3][0], s_acc[qf][3][1]),
                        (int)cvt_pk_bf16(s_acc[qf][3][2], s_acc[qf][3][3])};
            pa[qf][0] = __builtin_bit_cast(short8v, w0i);
            pa[qf][1] = __builtin_bit_cast(short8v, w1i);
        }

        if (kt < 31) {
            const int nxto = 4096 - bufo;
            *(uint4*)&Ks[nxto + srow * 64 + sgs * 8] = rk0;
            *(uint4*)&Ks[nxto + (srow + 32) * 64 + sgs * 8] = rk1;
            uint2 va0 = {rv0.x, rv0.y}, vb0 = {rv0.z, rv0.w};
            uint2 va1 = {rv1.x, rv1.y}, vb1 = {rv1.z, rv1.w};
            *(uint2*)&Vs[nxto + srow * 64 + (gv0 ^ vswz0) * 8 + vo] = va0;
            *(uint2*)&Vs[nxto + srow * 64 + ((gv0 + 1) ^ vswz0) * 8 + vo] = vb0;
            *(uint2*)&Vs[nxto + (srow + 32) * 64 + (gv0 ^ vswz0) * 8 + vo] = va1;
            *(uint2*)&Vs[nxto + (srow + 32) * 64 + ((gv0 + 1) ^ vswz0) * 8 + vo] = vb1;
        }

        // O += P @ V. Each bv read feeds both query fragments.
        __builtin_amdgcn_s_setprio(1);
#pragma unroll
        for (int dt = 0; dt < 4; dt++) {
            int r = dt * 16 + lo;
            short8v bv0 = *(const short8v*)&Vs[bufo + r * 64 + ((0 + hi) ^ (r & 7)) * 8];
            short8v bv1 = *(const short8v*)&Vs[bufo + r * 64 + ((4 + hi) ^ (r & 7)) * 8];
            o_acc[0][dt] = __builtin_amdgcn_mfma_f32_16x16x32_bf16(pa[0][0], bv0, o_acc[0][dt], 0, 0, 0);
            o_acc[0][dt] = __builtin_amdgcn_mfma_f32_16x16x32_bf16(pa[0][1], bv1, o_acc[0][dt], 0, 0, 0);
            o_acc[1][dt] = __builtin_amdgcn_mfma_f32_16x16x32_bf16(pa[1][0], bv0, o_acc[1][dt], 0, 0, 0);
            o_acc[1][dt] = __builtin_amdgcn_mfma_f32_16x16x32_bf16(pa[1][1], bv1, o_acc[1][dt], 0, 0, 0);
        }
        __builtin_amdgcn_s_setprio(0);
        __syncthreads();
    }

    // epilogue: reduce the partial l across the 4 row-lanes, then normalize
    const int b = bh >> 4, h = bh & 15;
#pragma unroll
    for (int qf = 0; qf < 2; qf++) {
        float ls = lp[qf];
        ls += __shfl_xor(ls, 16);
        ls += __shfl_xor(ls, 32);   // full l for query qf*16+lo, all lanes
#pragma unroll
        for (int reg = 0; reg < 4; reg++) {
            float lv = __shfl(ls, hi * 4 + reg);
            float inv = 1.0f / lv;
            int row = q0 + w * 32 + qf * 16 + hi * 4 + reg;
            ushort_t* orow = O + ((size_t)(b * 2048 + row)) * 1024 + h * 64;
#pragma unroll
            for (int dt = 0; dt < 4; dt++)
                orow[dt * 16 + lo] = to_bf16(o_acc[qf][dt][reg] * inv);
        }
    }
}

extern "C" void kernel_launch(void* const* d_in, const int* in_sizes, int n_in,
                              void* d_out, int out_size, void* d_ws, size_t ws_size,
                              hipStream_t stream) {
    const float* x      = (const float*)d_in[0];
    const float* qkv_w  = (const float*)d_in[1];
    const float* qkv_b  = (const float*)d_in[2];
    const float* proj_w = (const float*)d_in[3];
    const float* proj_b = (const float*)d_in[4];
    float* out = (float*)d_out;

    ushort_t* xb  = (ushort_t*)d_ws;        // 4,194,304  x bf16
    ushort_t* wqb = xb  + 4194304;          // 3,145,728  qkv_w bf16
    ushort_t* wpb = wqb + 3145728;          // 1,048,576  proj_w bf16
    ushort_t* qb  = wpb + 1048576;          // 4,194,304  Q (exp2-scaled)
    ushort_t* kb  = qb  + 4194304;          // 4,194,304  K
    ushort_t* vt  = kb  + 4194304;          // 4,194,304  V^T [BH][64][N]
    ushort_t* aob = vt  + 4194304;          // 4,194,304  attn out [M][1024]

    convert_kernel<<<4096, 256, 0, stream>>>(x, qkv_w, proj_w, xb, wqb, wpb);
    gemm_bf16_kernel<0, 128, 128><<<768, 256, 0, stream>>>(
        xb, wqb, qkv_b, qb, kb, vt, nullptr);
    attn_mfma_kernel<<<512, 256, 0, stream>>>(qb, kb, vt, aob);
    gemm_bf16_kernel<1, 64, 128><<<dim3(8, 64), 256, 0, stream>>>(
        aob, wpb, proj_b, nullptr, nullptr, nullptr, out);
}